// Round 4
// baseline (3815.094 us; speedup 1.0000x reference)
//
#include <hip/hip_runtime.h>
#include <math.h>

#define BB 64
#define TT 2048
#define II 256
#define HH 256
#define OO 128

typedef _Float16 half8 __attribute__((ext_vector_type(8)));
typedef float floatx4 __attribute__((ext_vector_type(4)));

__device__ __forceinline__ float fast_tanh(float x) {
    // 1 - 2/(e^{2x}+1): correct limits at +/-inf, ~1e-7 abs error
    float e = __expf(2.f * x);
    return 1.f - 2.f / (e + 1.f);
}

// ---------------------------------------------------------------------------
// Phase A GEMM: xpT[t][b][h] = x[b][t][:] . W_ih1[h][:] + b_ih1[h] + b_hh1[h]
// Output is T-MAJOR so each step's 16x256 xp block is contiguous per WG.
// Tile 128x128, BK=16, 256 threads, 8x8 microtile (round-2 kernel, new store).
// ---------------------------------------------------------------------------
__global__ __launch_bounds__(256)
void gemm_bias_T(const float* __restrict__ A, const float* __restrict__ W,
                 const float* __restrict__ b1, const float* __restrict__ b2,
                 float* __restrict__ C)
{
    constexpr int K = 256, N = 256;
    __shared__ float sA[16][132];
    __shared__ float sB[16][132];
    const int tid  = threadIdx.x;
    const long row0 = (long)blockIdx.x * 128;
    const int  col0 = blockIdx.y * 128;

    const int tm = tid & 15;
    const int tn = tid >> 4;

    float acc[8][8];
#pragma unroll
    for (int i = 0; i < 8; ++i)
#pragma unroll
        for (int j = 0; j < 8; ++j) acc[i][j] = 0.f;

    const int f0  = tid;
    const int f1  = tid + 256;
    const int am0 = f0 >> 2, ak0 = (f0 & 3) * 4;
    const int am1 = f1 >> 2, ak1 = (f1 & 3) * 4;

    for (int kt = 0; kt < K; kt += 16) {
        float4 a0 = *(const float4*)&A[(row0 + am0) * K + kt + ak0];
        float4 a1 = *(const float4*)&A[(row0 + am1) * K + kt + ak1];
        float4 w0 = *(const float4*)&W[(long)(col0 + am0) * K + kt + ak0];
        float4 w1 = *(const float4*)&W[(long)(col0 + am1) * K + kt + ak1];
        __syncthreads();
        sA[ak0+0][am0] = a0.x; sA[ak0+1][am0] = a0.y; sA[ak0+2][am0] = a0.z; sA[ak0+3][am0] = a0.w;
        sA[ak1+0][am1] = a1.x; sA[ak1+1][am1] = a1.y; sA[ak1+2][am1] = a1.z; sA[ak1+3][am1] = a1.w;
        sB[ak0+0][am0] = w0.x; sB[ak0+1][am0] = w0.y; sB[ak0+2][am0] = w0.z; sB[ak0+3][am0] = w0.w;
        sB[ak1+0][am1] = w1.x; sB[ak1+1][am1] = w1.y; sB[ak1+2][am1] = w1.z; sB[ak1+3][am1] = w1.w;
        __syncthreads();
#pragma unroll
        for (int k = 0; k < 16; ++k) {
            float4 av0 = *(const float4*)&sA[k][tm * 8];
            float4 av1 = *(const float4*)&sA[k][tm * 8 + 4];
            float4 bv0 = *(const float4*)&sB[k][tn * 8];
            float4 bv1 = *(const float4*)&sB[k][tn * 8 + 4];
            float am[8] = {av0.x, av0.y, av0.z, av0.w, av1.x, av1.y, av1.z, av1.w};
            float bn[8] = {bv0.x, bv0.y, bv0.z, bv0.w, bv1.x, bv1.y, bv1.z, bv1.w};
#pragma unroll
            for (int i = 0; i < 8; ++i)
#pragma unroll
                for (int j = 0; j < 8; ++j)
                    acc[i][j] += am[i] * bn[j];
        }
    }

    float bias[8];
#pragma unroll
    for (int j = 0; j < 8; ++j) {
        int col = col0 + tn * 8 + j;
        bias[j] = b1[col] + b2[col];
    }
#pragma unroll
    for (int i = 0; i < 8; ++i) {
        long row  = row0 + tm * 8 + i;              // row = b*TT + t
        long bidx = row >> 11;                      // / TT
        long tidx = row & 2047;                     // % TT
        float* op = &C[(tidx * BB + bidx) * 256 + col0 + tn * 8];
        float4 v0, v1;
        v0.x = acc[i][0] + bias[0]; v0.y = acc[i][1] + bias[1];
        v0.z = acc[i][2] + bias[2]; v0.w = acc[i][3] + bias[3];
        v1.x = acc[i][4] + bias[4]; v1.y = acc[i][5] + bias[5];
        v1.z = acc[i][6] + bias[6]; v1.w = acc[i][7] + bias[7];
        *(float4*)op       = v0;
        *(float4*)(op + 4) = v1;
    }
}

// ---------------------------------------------------------------------------
// MFMA-pipelined RNN. 8 WGs x 256 threads (4 waves), one WG per CU.
//  WG p in [0,4):  producer — layer-1 for batches [p*16, p*16+16).
//    Per step: 16x256x256 f16 MFMA (A = h_{t-1} from LDS, B = W_hh1 in regs,
//    wave w owns N-slice w*64). z = C + xp (fp32, exact). h_t -> LDS (f16)
//    and global (f16, overlaid into the consumed xpT[t] rows).
//  WG p+4:  consumer — layer-2 for the same batches: o_t = tanh(W_ih2 h1_t
//    + W_hh2 o_{t-1} + bias), both weight sets f16 in regs, single fp32
//    accumulator chain; trails producer via flags[p] (released every 8 steps).
// MFMA layouts (verified, m89/m120): A[m=lane&15][k=quad*8+j],
// B[n=lane&15][k=quad*8+j] from row-major [N][K], C: col(n)=lane&15,
// row(m)=quad*4+reg.
// ---------------------------------------------------------------------------
__global__ __launch_bounds__(256, 1)
void rnn_pipe(const float* __restrict__ W_hh1,
              const float* __restrict__ W_ih2,
              const float* __restrict__ W_hh2,
              const float* __restrict__ b_ih2,
              const float* __restrict__ b_hh2,
              float* __restrict__ XP,      // xpT [t][64][256] fp32; h1 f16 overlay
              float* __restrict__ out,     // [b*TT + t][OO] fp32
              int* __restrict__ flags)     // [4], pre-zeroed
{
    const int tid  = threadIdx.x;
    const int wave = tid >> 6;
    const int lane = tid & 63;
    const int q    = lane >> 4;      // quad 0..3
    const int l15  = lane & 15;

    if (blockIdx.x < 4) {
        // ============================ producer ============================
        const int p  = blockIdx.x;
        const int m0 = p * 16;
        const int n0 = wave * 64;                    // N-slice of this wave
        __shared__ _Float16 hbuf[16 * 264];          // h state, +8 f16 row pad

        // B-frags: W_hh1 rows n0..n0+63, f16, register-resident (128 VGPR)
        half8 bf[4][8];
#pragma unroll
        for (int j = 0; j < 4; ++j)
#pragma unroll
            for (int s = 0; s < 8; ++s) {
                const float* wp = W_hh1 + (long)(n0 + j * 16 + l15) * 256 + s * 32 + q * 8;
                float4 u0 = *(const float4*)wp;
                float4 u1 = *(const float4*)(wp + 4);
                half8 h;
                h[0] = (_Float16)u0.x; h[1] = (_Float16)u0.y;
                h[2] = (_Float16)u0.z; h[3] = (_Float16)u0.w;
                h[4] = (_Float16)u1.x; h[5] = (_Float16)u1.y;
                h[6] = (_Float16)u1.z; h[7] = (_Float16)u1.w;
                bf[j][s] = h;
            }

        for (int i = tid; i < 16 * 264; i += 256) hbuf[i] = (_Float16)0.f;

        // prefetch xp[0] (fp32, exact drive term)
        float xpn[4][4];
#pragma unroll
        for (int j = 0; j < 4; ++j)
#pragma unroll
            for (int i = 0; i < 4; ++i)
                xpn[j][i] = XP[((long)0 * BB + m0 + q * 4 + i) * 256 + n0 + j * 16 + l15];
        __syncthreads();

        for (int t = 0; t < TT; ++t) {
            // ---- A-frags from LDS + MFMA ----
            half8 a[8];
#pragma unroll
            for (int s = 0; s < 8; ++s)
                a[s] = *(const half8*)&hbuf[l15 * 264 + s * 32 + q * 8];

            floatx4 c[4] = {{0.f,0.f,0.f,0.f},{0.f,0.f,0.f,0.f},
                            {0.f,0.f,0.f,0.f},{0.f,0.f,0.f,0.f}};
#pragma unroll
            for (int s = 0; s < 8; ++s)
#pragma unroll
                for (int j = 0; j < 4; ++j)
                    c[j] = __builtin_amdgcn_mfma_f32_16x16x32_f16(a[s], bf[j][s], c[j], 0, 0, 0);

            __syncthreads();   // A-reads of h_{t-1} done before overwrite

            // publish: after this barrier all global h1 stores of steps < t
            // are drained; release@agent wbl2's them to the coherence point
            if ((t & 7) == 0 && t > 0 && tid == 0)
                __hip_atomic_store(&flags[p], t, __ATOMIC_RELEASE,
                                   __HIP_MEMORY_SCOPE_AGENT);

            // ---- epilogue: z = C + xp, tanh, write h_t to LDS (f16) ----
#pragma unroll
            for (int j = 0; j < 4; ++j)
#pragma unroll
                for (int i = 0; i < 4; ++i) {
                    float v = fast_tanh(c[j][i] + xpn[j][i]);
                    hbuf[(q * 4 + i) * 264 + n0 + j * 16 + l15] = (_Float16)v;
                }
            __syncthreads();

            // ---- h_t -> global f16 (overlay into consumed xpT[t] rows) ----
            {
                const int r   = tid >> 4;            // row 0..15
                const int o16 = (tid & 15) * 16;     // 16 f16 = 32 B
                half8 v0 = *(const half8*)&hbuf[r * 264 + o16];
                half8 v1 = *(const half8*)&hbuf[r * 264 + o16 + 8];
                _Float16* gp = (_Float16*)(XP + ((long)t * BB + m0 + r) * 256) + o16;
                *(half8*)gp       = v0;
                *(half8*)(gp + 8) = v1;
            }
            // ---- prefetch xp[t+1] ----
            if (t + 1 < TT) {
#pragma unroll
                for (int j = 0; j < 4; ++j)
#pragma unroll
                    for (int i = 0; i < 4; ++i)
                        xpn[j][i] = XP[((long)(t + 1) * BB + m0 + q * 4 + i) * 256
                                       + n0 + j * 16 + l15];
            }
        }
        __syncthreads();
        if (tid == 0)
            __hip_atomic_store(&flags[p], TT, __ATOMIC_RELEASE,
                               __HIP_MEMORY_SCOPE_AGENT);
    } else {
        // ============================ consumer ============================
        const int p  = blockIdx.x - 4;
        const int m0 = p * 16;
        const int n0 = wave * 32;                    // o-slice of this wave
        __shared__ _Float16 obuf[16 * 136];          // o state, +8 f16 row pad

        // B1 = W_ih2 (128x256), B2 = W_hh2 (128x128), f16 in regs (96 VGPR)
        half8 bf1[2][8];
        half8 bf2[2][4];
#pragma unroll
        for (int j = 0; j < 2; ++j) {
#pragma unroll
            for (int s = 0; s < 8; ++s) {
                const float* wp = W_ih2 + (long)(n0 + j * 16 + l15) * 256 + s * 32 + q * 8;
                float4 u0 = *(const float4*)wp;
                float4 u1 = *(const float4*)(wp + 4);
                half8 h;
                h[0] = (_Float16)u0.x; h[1] = (_Float16)u0.y;
                h[2] = (_Float16)u0.z; h[3] = (_Float16)u0.w;
                h[4] = (_Float16)u1.x; h[5] = (_Float16)u1.y;
                h[6] = (_Float16)u1.z; h[7] = (_Float16)u1.w;
                bf1[j][s] = h;
            }
#pragma unroll
            for (int s = 0; s < 4; ++s) {
                const float* wp = W_hh2 + (long)(n0 + j * 16 + l15) * 128 + s * 32 + q * 8;
                float4 u0 = *(const float4*)wp;
                float4 u1 = *(const float4*)(wp + 4);
                half8 h;
                h[0] = (_Float16)u0.x; h[1] = (_Float16)u0.y;
                h[2] = (_Float16)u0.z; h[3] = (_Float16)u0.w;
                h[4] = (_Float16)u1.x; h[5] = (_Float16)u1.y;
                h[6] = (_Float16)u1.z; h[7] = (_Float16)u1.w;
                bf2[j][s] = h;
            }
        }

        float bias[2];
#pragma unroll
        for (int j = 0; j < 2; ++j)
            bias[j] = b_ih2[n0 + j * 16 + l15] + b_hh2[n0 + j * 16 + l15];

        for (int i = tid; i < 16 * 136; i += 256) obuf[i] = (_Float16)0.f;
        __syncthreads();

        int seen = 0;
        bool have = false;
        half8 a1[8];

        for (int t = 0; t < TT; ++t) {
            if (!have) {
                if (seen <= t) {
                    do {
                        seen = __hip_atomic_load(&flags[p], __ATOMIC_ACQUIRE,
                                                 __HIP_MEMORY_SCOPE_AGENT);
                    } while (seen <= t);
                }
                const _Float16* h1p =
                    (const _Float16*)(XP + ((long)t * BB + m0 + l15) * 256);
#pragma unroll
                for (int s = 0; s < 8; ++s)
                    a1[s] = *(const half8*)(h1p + s * 32 + q * 8);
            }

            half8 a2[4];
#pragma unroll
            for (int s = 0; s < 4; ++s)
                a2[s] = *(const half8*)&obuf[l15 * 136 + s * 32 + q * 8];

            floatx4 c[2] = {{0.f,0.f,0.f,0.f},{0.f,0.f,0.f,0.f}};
#pragma unroll
            for (int s = 0; s < 8; ++s)
#pragma unroll
                for (int j = 0; j < 2; ++j)
                    c[j] = __builtin_amdgcn_mfma_f32_16x16x32_f16(a1[s], bf1[j][s], c[j], 0, 0, 0);
#pragma unroll
            for (int s = 0; s < 4; ++s)
#pragma unroll
                for (int j = 0; j < 2; ++j)
                    c[j] = __builtin_amdgcn_mfma_f32_16x16x32_f16(a2[s], bf2[j][s], c[j], 0, 0, 0);

            __syncthreads();   // a2 reads of o_{t-1} done before overwrite

#pragma unroll
            for (int j = 0; j < 2; ++j)
#pragma unroll
                for (int i = 0; i < 4; ++i) {
                    float v = fast_tanh(c[j][i] + bias[j]);
                    obuf[(q * 4 + i) * 136 + n0 + j * 16 + l15] = (_Float16)v;
                    out[((long)(m0 + q * 4 + i) * TT + t) * OO + n0 + j * 16 + l15] = v;
                }
            __syncthreads();

            // prefetch next step's h1 frags if already published
            have = false;
            if (t + 1 < TT && seen > t + 1) {
                const _Float16* h1p =
                    (const _Float16*)(XP + ((long)(t + 1) * BB + m0 + l15) * 256);
#pragma unroll
                for (int s = 0; s < 8; ++s)
                    a1[s] = *(const half8*)(h1p + s * 32 + q * 8);
                have = true;
            }
        }
    }
}

// ---------------------------------------------------------------------------
extern "C" void kernel_launch(void* const* d_in, const int* in_sizes, int n_in,
                              void* d_out, int out_size, void* d_ws, size_t ws_size,
                              hipStream_t stream)
{
    const float* x     = (const float*)d_in[0];
    const float* W_ih1 = (const float*)d_in[1];
    const float* W_hh1 = (const float*)d_in[2];
    const float* b_ih1 = (const float*)d_in[3];
    const float* b_hh1 = (const float*)d_in[4];
    const float* W_ih2 = (const float*)d_in[5];
    const float* W_hh2 = (const float*)d_in[6];
    const float* b_ih2 = (const float*)d_in[7];
    const float* b_hh2 = (const float*)d_in[8];
    float* out = (float*)d_out;

    float* xpT = (float*)d_ws;                          // [T][64][256] fp32 = 128 MiB
    const size_t FLAG_OFF = (size_t)TT * BB * HH * sizeof(float);
    int* flags = (int*)((char*)d_ws + FLAG_OFF);        // [4]

    hipMemsetAsync(flags, 0, 4 * sizeof(int), stream);

    // Phase A: xpT[t][b][:] = x[b][t][:] @ W_ih1^T + b_ih1 + b_hh1
    dim3 gA(BB * TT / 128, HH / 128);
    gemm_bias_T<<<gA, 256, 0, stream>>>(x, W_ih1, b_ih1, b_hh1, xpT);

    // Phase B: MFMA producers (layer 1) + consumers (layer 2), pipelined
    rnn_pipe<<<8, 256, 0, stream>>>(W_hh1, W_ih2, W_hh2, b_ih2, b_hh2,
                                    xpT, out, flags);
}